// Round 8
// baseline (526.418 us; speedup 1.0000x reference)
//
#include <hip/hip_runtime.h>

#define RHO_C 10.0f
#define SIGMA_C 1e-6f
#define PEN_C 1000.0f
#define ITERS_C 200

typedef float f32x2 __attribute__((ext_vector_type(2)));
// D = S0*S1 + D (packed 2xfp32, VOP3P)
#define PKFMA(acc, a, b) \
  asm("v_pk_fma_f32 %0, %1, %2, %0" : "+v"(acc) : "v"(a), "v"(b))

// One sample per block, 256 threads (4 waves), 4 blocks/CU.
// 3-barrier iteration (was 6): every matvec output is owned by ONE wave
// (3-lane groups for A^T u and K^{-1} rhs, 2-lane groups for A z) and reduced
// with __shfl_down — no psum LDS round-trips. Constraint update fused into
// stage C; rows 85..168 of G (identity blocks) on spare lanes. All matrices
// register-resident in the loop (at2 / kreg2 / crow2); LDS carries only
// broadcast vectors (u, rhs, z).
__launch_bounds__(256, 4)
__global__ void qp_admm_kernel(const float* __restrict__ xraw,
                               const float* __restrict__ Ag,
                               const float* __restrict__ bg,
                               const float* __restrict__ lowg,
                               float* __restrict__ outp) {
  const int s = blockIdx.x;
  const int t = threadIdx.x;
  const int w = t >> 6, l = t & 63;
  const float* A = Ag + (size_t)s * (85 * 80);

  __shared__ __align__(16) float nA[85 * 84];   // pitch 84, cols 80..83 zero
  __shared__ __align__(16) float xr[80];
  __shared__ __align__(16) float rinv[88];
  __shared__ __align__(16) float u_lds[176];
  __shared__ __align__(16) float rhs_lds[84];
  __shared__ __align__(16) float z_lds[84];
  __shared__ __align__(16) float rkbuf[2][84];
  __shared__ __align__(16) float psq[256];

  // role indices (all wave-local groups)
  const int  SROW = w * 21 + l / 3;   // K row (sweep + stage B), l<63
  const int  SP   = l % 3;            // 28-col chunk of K row
  const bool bval = (l < 63);
  const int  CA   = w * 20 + l / 3;   // A^T column (stage A), l<60
  const int  PA   = l % 3;            // row-chunk {0..27,28..55,56..84}
  const bool aval = (l < 60);
  const bool hasrow = (w < 2) || (w == 2 && l < 42);
  const int  rowC = (w < 2) ? (w * 32 + (l >> 1)) : (64 + (l >> 1));
  const int  QC   = l & 1;            // 40-col half of the A-row dot
  const bool isx  = (w == 3) || (w == 2 && l >= 42 && l < 62);
  const int  eidx = (w == 3) ? l : (64 + l - 42);   // extra constraint 85+eidx

  if (t < 84) z_lds[t] = 0.f;
  if (t < 176) u_lds[t] = 0.f;
  if (t < 80) xr[t] = xraw[s * 80 + t];
  for (int e = t; e < 85 * 84; e += 256) {
    int r = e / 84, c = e - r * 84;
    nA[e] = (c < 80) ? A[r * 80 + c] : 0.f;
  }
  __syncthreads();

  // ---- row norms (255 threads, 3 partials/row)
  if (t < 255) {
    int r = t / 3, p = t - 3 * r;
    int c0 = p * 27, len = (p == 2) ? 26 : 27;
    float acc = 0.f;
    for (int k = 0; k < len; ++k) { float v = nA[r * 84 + c0 + k]; acc += v * v; }
    psq[t] = acc;
  }
  __syncthreads();
  if (t < 85) {
    float n2 = psq[3 * t] + psq[3 * t + 1] + psq[3 * t + 2];
    rinv[t] = 1.0f / fmaxf(sqrtf(n2), 1e-12f);
  }
  __syncthreads();
  for (int e = t; e < 85 * 84; e += 256) nA[e] *= rinv[e / 84];
  __syncthreads();

  // ---- K = RHO*G^T G + diag(pdiag+SIGMA): thread (SROW,SP) = row SROW cols [28SP,+28)
  float kreg[28];
#pragma unroll
  for (int jj = 0; jj < 28; ++jj) kreg[jj] = 0.f;
  if (bval && SROW < 80) {
    for (int r = 0; r < 85; ++r) {
      float ai = nA[r * 84 + SROW];
      const float4* rv = (const float4*)&nA[r * 84 + SP * 28];
#pragma unroll
      for (int q = 0; q < 7; ++q) {
        float4 v = rv[q];
        kreg[4*q+0] += ai * v.x; kreg[4*q+1] += ai * v.y;
        kreg[4*q+2] += ai * v.z; kreg[4*q+3] += ai * v.w;
      }
    }
  }
  if (bval) {
#pragma unroll
    for (int jj = 0; jj < 28; ++jj) {
      int j = SP * 28 + jj;
      float v;
      if (SROW < 80) {
        v = (j < 80)
              ? (RHO_C * kreg[jj] + ((j == SROW) ? (RHO_C + 1.0f + SIGMA_C) : 0.f))
              : (-RHO_C * nA[(81 + (j - 80)) * 84 + SROW]);
      } else {
        int ss = SROW - 80;
        v = (j < 80) ? (-RHO_C * nA[(81 + ss) * 84 + j])
                     : ((j - 80 == ss) ? (2.f*RHO_C + 2.f*PEN_C + SIGMA_C) : 0.f);
      }
      kreg[jj] = v;
    }
    if (SROW == 0) {
#pragma unroll
      for (int jj = 0; jj < 28; ++jj) rkbuf[0][SP * 28 + jj] = kreg[jj];
    }
  }
  __syncthreads();

  // ---- SPD Gauss-Jordan sweep; final kreg = -K^{-1} row chunk
  for (int k = 0; k < 84; ++k) {
    const float* rk = rkbuf[k & 1];
    float dinv = 1.0f / rk[k];
    if (bval) {
      float t1 = rk[SROW] * dinv;
      bool rowk = (SROW == k);
      int jfix = k - SP * 28;
      const float4* rkv = (const float4*)&rk[SP * 28];
      float rkrow[28];
#pragma unroll
      for (int q = 0; q < 7; ++q) {
        float4 v = rkv[q];
        rkrow[4*q+0]=v.x; rkrow[4*q+1]=v.y; rkrow[4*q+2]=v.z; rkrow[4*q+3]=v.w;
      }
#pragma unroll
      for (int jj = 0; jj < 28; ++jj) {
        float rkj = rkrow[jj];
        float gen = kreg[jj] - t1 * rkj;
        kreg[jj] = rowk ? ((jj == jfix) ? -dinv : rkj * dinv)
                        : ((jj == jfix) ? t1 : gen);
      }
      if (k < 83 && SROW == k + 1) {
        float4* wv = (float4*)&rkbuf[(k + 1) & 1][SP * 28];
#pragma unroll
        for (int q = 0; q < 7; ++q)
          wv[q] = make_float4(kreg[4*q], kreg[4*q+1], kreg[4*q+2], kreg[4*q+3]);
      }
    }
    __syncthreads();
  }

  f32x2 kreg2[14];
#pragma unroll
  for (int q = 0; q < 7; ++q) {
    kreg2[2*q]   = (f32x2){kreg[4*q],   kreg[4*q+1]};
    kreg2[2*q+1] = (f32x2){kreg[4*q+2], kreg[4*q+3]};
  }

  // ---- register A^T chunks (stage A): col CA, rows [28PA, +28(+1))
  f32x2 at2[14]; float a84 = 0.f;
  {
    int r0 = PA * 28;
#pragma unroll
    for (int q = 0; q < 7; ++q) {
      float v0 = aval ? nA[(r0 + 4*q + 0) * 84 + CA] : 0.f;
      float v1 = aval ? nA[(r0 + 4*q + 1) * 84 + CA] : 0.f;
      float v2 = aval ? nA[(r0 + 4*q + 2) * 84 + CA] : 0.f;
      float v3 = aval ? nA[(r0 + 4*q + 3) * 84 + CA] : 0.f;
      at2[2*q]   = (f32x2){v0, v1};
      at2[2*q+1] = (f32x2){v2, v3};
    }
    if (aval && PA == 2) a84 = nA[84 * 84 + CA];
  }
  // ---- register A-row chunks (stage C): row rowC, cols [40QC, +40)
  f32x2 crow2[20];
#pragma unroll
  for (int q = 0; q < 20; ++q) crow2[q] = (f32x2){0.f, 0.f};
  if (hasrow) {
    const float4* av = (const float4*)&nA[rowC * 84 + QC * 40];
#pragma unroll
    for (int q = 0; q < 10; ++q) {
      float4 v = av[q];
      crow2[2*q]   = (f32x2){v.x, v.y};
      crow2[2*q+1] = (f32x2){v.z, v.w};
    }
  }

  float yor = 0.f, h = 0.f;
  if (hasrow && QC == 0) h = bg[s * 85 + rowC] * rinv[rowC];
  if (isx) h = (eidx < 4) ? 0.f : -lowg[s * 80 + (eidx - 4)];

  // ---- 200 ADMM iterations, 3 barriers each
  for (int it = 0; it < ITERS_C; ++it) {
    // stage A: rhs = SIGMA z - q + G^T u   (A^T in regs, u broadcast b128)
    {
      float part = 0.f;
      if (aval) {
        const float4* ub = (const float4*)&u_lds[PA * 28];
        f32x2 acc = {0.f, 0.f};
#pragma unroll
        for (int q = 0; q < 7; ++q) {
          float4 uv = ub[q];
          f32x2 ulo = (f32x2){uv.x, uv.y}, uhi = (f32x2){uv.z, uv.w};
          PKFMA(acc, at2[2*q],   ulo);
          PKFMA(acc, at2[2*q+1], uhi);
        }
        part = acc.x + acc.y;
        if (PA == 2) part += a84 * u_lds[84];
      }
      float s1 = __shfl_down(part, 1);
      float s2 = __shfl_down(part, 2);
      if (aval && PA == 0)
        rhs_lds[CA] = (part + s1 + s2) + xr[CA] + SIGMA_C * z_lds[CA] - u_lds[89 + CA];
      if (w == 0 && l >= 60) {
        int ss = l - 60;
        rhs_lds[80 + ss] = SIGMA_C * z_lds[80 + ss] - u_lds[81 + ss] - u_lds[85 + ss];
      }
    }
    __syncthreads();
    // stage B: z = K^{-1} rhs   (-K^{-1} in regs, rhs broadcast b128)
    {
      float part = 0.f;
      if (bval) {
        const float4* rc = (const float4*)&rhs_lds[SP * 28];
        f32x2 acc = {0.f, 0.f};
#pragma unroll
        for (int q = 0; q < 7; ++q) {
          float4 rv = rc[q];
          f32x2 rlo = (f32x2){rv.x, rv.y}, rhi = (f32x2){rv.z, rv.w};
          PKFMA(acc, kreg2[2*q],   rlo);
          PKFMA(acc, kreg2[2*q+1], rhi);
        }
        part = acc.x + acc.y;
      }
      float s1 = __shfl_down(part, 1);
      float s2 = __shfl_down(part, 2);
      if (bval && SP == 0) z_lds[SROW] = -(part + s1 + s2);
    }
    __syncthreads();
    // stage C + update: gz rows via 2-lane dots; identity constraints on spares
    {
      float part = 0.f;
      if (hasrow) {
        const float4* zb = (const float4*)&z_lds[QC * 40];
        f32x2 acc = {0.f, 0.f};
#pragma unroll
        for (int q = 0; q < 10; ++q) {
          float4 zv = zb[q];
          f32x2 zlo = (f32x2){zv.x, zv.y}, zhi = (f32x2){zv.z, zv.w};
          PKFMA(acc, crow2[2*q],   zlo);
          PKFMA(acc, crow2[2*q+1], zhi);
        }
        part = acc.x + acc.y;
      }
      float s1 = __shfl_down(part, 1);
      if (hasrow && QC == 0) {
        float gz = part + s1;
        if (rowC >= 81) gz -= z_lds[80 + (rowC - 81)];   // soft rows: -s term
        float v = gz + yor;
        float wv = fminf(v, h);
        u_lds[rowC] = RHO_C * (2.f * wv - v);
        yor = v - wv;
      }
      if (isx) {
        int zi = (eidx < 4) ? (80 + eidx) : (eidx - 4);
        float gz = -z_lds[zi];
        float v = gz + yor;
        float wv = fminf(v, h);
        u_lds[85 + eidx] = RHO_C * (2.f * wv - v);
        yor = v - wv;
      }
    }
    __syncthreads();
  }

  if (t < 80) outp[s * 80 + t] = z_lds[t];
}

extern "C" void kernel_launch(void* const* d_in, const int* in_sizes, int n_in,
                              void* d_out, int out_size, void* d_ws, size_t ws_size,
                              hipStream_t stream) {
  const float* xraw = (const float*)d_in[0];
  const float* Ag   = (const float*)d_in[1];
  const float* bg   = (const float*)d_in[2];
  const float* lowg = (const float*)d_in[3];
  float* outp = (float*)d_out;
  const int B = in_sizes[0] / 80;
  qp_admm_kernel<<<B, 256, 0, stream>>>(xraw, Ag, bg, lowg, outp);
}

// Round 9
// 471.918 us; speedup vs baseline: 1.1155x; 1.1155x over previous
//
#include <hip/hip_runtime.h>

#define RHO_C 10.0f
#define SIGMA_C 1e-6f
#define PEN_C 1000.0f
#define ITERS_C 200

typedef float f32x2 __attribute__((ext_vector_type(2)));
// D = S0*S1 + D (packed 2xfp32, VOP3P)
#define PKFMA(acc, a, b) \
  asm("v_pk_fma_f32 %0, %1, %2, %0" : "+v"(acc) : "v"(a), "v"(b))

// One sample per block, 256 threads (4 waves), 4 blocks/CU.
// 3-barrier iteration: each matvec output owned by ONE wave (3-lane groups
// for A^T u and K^{-1} rhs, 2-lane groups for A z), reduced via __shfl_down.
// Registers hold only at2 (A^T chunk, 29) + kreg2 (-K^{-1} rows, 28): R8's
// crow2[40] pushed past the 128-reg budget and spilled to scratch (+19MB HBM,
// +70us) — stage C reads A rows from LDS instead (pitch-84 mapping is
// conflict-free: b128 starts land on the 8 aligned 4-bank spans, 8 lanes each).
__launch_bounds__(256, 4)
__global__ void qp_admm_kernel(const float* __restrict__ xraw,
                               const float* __restrict__ Ag,
                               const float* __restrict__ bg,
                               const float* __restrict__ lowg,
                               float* __restrict__ outp) {
  const int s = blockIdx.x;
  const int t = threadIdx.x;
  const int w = t >> 6, l = t & 63;
  const float* A = Ag + (size_t)s * (85 * 80);

  __shared__ __align__(16) float nA[85 * 84];   // pitch 84, cols 80..83 zero
  __shared__ __align__(16) float xr[80];
  __shared__ __align__(16) float rinv[88];
  __shared__ __align__(16) float u_lds[176];
  __shared__ __align__(16) float rhs_lds[84];
  __shared__ __align__(16) float z_lds[84];
  __shared__ __align__(16) float rkbuf[2][84];
  __shared__ __align__(16) float psq[256];

  // role indices (all wave-local groups)
  const int  SROW = w * 21 + l / 3;   // K row (sweep + stage B), l<63
  const int  SP   = l % 3;            // 28-col chunk of K row
  const bool bval = (l < 63);
  const int  CA   = w * 20 + l / 3;   // A^T column (stage A), l<60
  const int  PA   = l % 3;            // row-chunk {0..27,28..55,56..84}
  const bool aval = (l < 60);
  const bool hasrow = (w < 2) || (w == 2 && l < 42);
  const int  rowC = (w < 2) ? (w * 32 + (l >> 1)) : (64 + (l >> 1));
  const int  QC   = l & 1;            // 40-col half of the A-row dot
  const bool isx  = (w == 3) || (w == 2 && l >= 42 && l < 62);
  const int  eidx = (w == 3) ? l : (64 + l - 42);   // extra constraint 85+eidx

  if (t < 84) z_lds[t] = 0.f;
  if (t < 176) u_lds[t] = 0.f;
  if (t < 80) xr[t] = xraw[s * 80 + t];
  for (int e = t; e < 85 * 84; e += 256) {
    int r = e / 84, c = e - r * 84;
    nA[e] = (c < 80) ? A[r * 80 + c] : 0.f;
  }
  __syncthreads();

  // ---- row norms (255 threads, 3 partials/row)
  if (t < 255) {
    int r = t / 3, p = t - 3 * r;
    int c0 = p * 27, len = (p == 2) ? 26 : 27;
    float acc = 0.f;
    for (int k = 0; k < len; ++k) { float v = nA[r * 84 + c0 + k]; acc += v * v; }
    psq[t] = acc;
  }
  __syncthreads();
  if (t < 85) {
    float n2 = psq[3 * t] + psq[3 * t + 1] + psq[3 * t + 2];
    rinv[t] = 1.0f / fmaxf(sqrtf(n2), 1e-12f);
  }
  __syncthreads();
  for (int e = t; e < 85 * 84; e += 256) nA[e] *= rinv[e / 84];
  __syncthreads();

  // ---- K = RHO*G^T G + diag(pdiag+SIGMA): thread (SROW,SP) = row SROW cols [28SP,+28)
  float kreg[28];
#pragma unroll
  for (int jj = 0; jj < 28; ++jj) kreg[jj] = 0.f;
  if (bval && SROW < 80) {
    for (int r = 0; r < 85; ++r) {
      float ai = nA[r * 84 + SROW];
      const float4* rv = (const float4*)&nA[r * 84 + SP * 28];
#pragma unroll
      for (int q = 0; q < 7; ++q) {
        float4 v = rv[q];
        kreg[4*q+0] += ai * v.x; kreg[4*q+1] += ai * v.y;
        kreg[4*q+2] += ai * v.z; kreg[4*q+3] += ai * v.w;
      }
    }
  }
  if (bval) {
#pragma unroll
    for (int jj = 0; jj < 28; ++jj) {
      int j = SP * 28 + jj;
      float v;
      if (SROW < 80) {
        v = (j < 80)
              ? (RHO_C * kreg[jj] + ((j == SROW) ? (RHO_C + 1.0f + SIGMA_C) : 0.f))
              : (-RHO_C * nA[(81 + (j - 80)) * 84 + SROW]);
      } else {
        int ss = SROW - 80;
        v = (j < 80) ? (-RHO_C * nA[(81 + ss) * 84 + j])
                     : ((j - 80 == ss) ? (2.f*RHO_C + 2.f*PEN_C + SIGMA_C) : 0.f);
      }
      kreg[jj] = v;
    }
    if (SROW == 0) {
#pragma unroll
      for (int jj = 0; jj < 28; ++jj) rkbuf[0][SP * 28 + jj] = kreg[jj];
    }
  }
  __syncthreads();

  // ---- SPD Gauss-Jordan sweep; final kreg = -K^{-1} row chunk
  for (int k = 0; k < 84; ++k) {
    const float* rk = rkbuf[k & 1];
    float dinv = 1.0f / rk[k];
    if (bval) {
      float t1 = rk[SROW] * dinv;
      bool rowk = (SROW == k);
      int jfix = k - SP * 28;
      const float4* rkv = (const float4*)&rk[SP * 28];
      float rkrow[28];
#pragma unroll
      for (int q = 0; q < 7; ++q) {
        float4 v = rkv[q];
        rkrow[4*q+0]=v.x; rkrow[4*q+1]=v.y; rkrow[4*q+2]=v.z; rkrow[4*q+3]=v.w;
      }
#pragma unroll
      for (int jj = 0; jj < 28; ++jj) {
        float rkj = rkrow[jj];
        float gen = kreg[jj] - t1 * rkj;
        kreg[jj] = rowk ? ((jj == jfix) ? -dinv : rkj * dinv)
                        : ((jj == jfix) ? t1 : gen);
      }
      if (k < 83 && SROW == k + 1) {
        float4* wv = (float4*)&rkbuf[(k + 1) & 1][SP * 28];
#pragma unroll
        for (int q = 0; q < 7; ++q)
          wv[q] = make_float4(kreg[4*q], kreg[4*q+1], kreg[4*q+2], kreg[4*q+3]);
      }
    }
    __syncthreads();
  }

  f32x2 kreg2[14];
#pragma unroll
  for (int q = 0; q < 7; ++q) {
    kreg2[2*q]   = (f32x2){kreg[4*q],   kreg[4*q+1]};
    kreg2[2*q+1] = (f32x2){kreg[4*q+2], kreg[4*q+3]};
  }

  // ---- register A^T chunks (stage A): col CA, rows [28PA, +28(+1))
  f32x2 at2[14]; float a84 = 0.f;
  {
    int r0 = PA * 28;
#pragma unroll
    for (int q = 0; q < 7; ++q) {
      float v0 = aval ? nA[(r0 + 4*q + 0) * 84 + CA] : 0.f;
      float v1 = aval ? nA[(r0 + 4*q + 1) * 84 + CA] : 0.f;
      float v2 = aval ? nA[(r0 + 4*q + 2) * 84 + CA] : 0.f;
      float v3 = aval ? nA[(r0 + 4*q + 3) * 84 + CA] : 0.f;
      at2[2*q]   = (f32x2){v0, v1};
      at2[2*q+1] = (f32x2){v2, v3};
    }
    if (aval && PA == 2) a84 = nA[84 * 84 + CA];
  }

  float yor = 0.f, h = 0.f;
  if (hasrow && QC == 0) h = bg[s * 85 + rowC] * rinv[rowC];
  if (isx) h = (eidx < 4) ? 0.f : -lowg[s * 80 + (eidx - 4)];

  // ---- 200 ADMM iterations, 3 barriers each
  for (int it = 0; it < ITERS_C; ++it) {
    // stage A: rhs = SIGMA z - q + G^T u   (A^T in regs, u broadcast b128)
    {
      float part = 0.f;
      if (aval) {
        const float4* ub = (const float4*)&u_lds[PA * 28];
        f32x2 acc = {0.f, 0.f};
#pragma unroll
        for (int q = 0; q < 7; ++q) {
          float4 uv = ub[q];
          f32x2 ulo = (f32x2){uv.x, uv.y}, uhi = (f32x2){uv.z, uv.w};
          PKFMA(acc, at2[2*q],   ulo);
          PKFMA(acc, at2[2*q+1], uhi);
        }
        part = acc.x + acc.y;
        if (PA == 2) part += a84 * u_lds[84];
      }
      float s1 = __shfl_down(part, 1);
      float s2 = __shfl_down(part, 2);
      if (aval && PA == 0)
        rhs_lds[CA] = (part + s1 + s2) + xr[CA] + SIGMA_C * z_lds[CA] - u_lds[89 + CA];
      if (w == 0 && l >= 60) {
        int ss = l - 60;
        rhs_lds[80 + ss] = SIGMA_C * z_lds[80 + ss] - u_lds[81 + ss] - u_lds[85 + ss];
      }
    }
    __syncthreads();
    // stage B: z = K^{-1} rhs   (-K^{-1} in regs, rhs broadcast b128)
    {
      float part = 0.f;
      if (bval) {
        const float4* rc = (const float4*)&rhs_lds[SP * 28];
        f32x2 acc = {0.f, 0.f};
#pragma unroll
        for (int q = 0; q < 7; ++q) {
          float4 rv = rc[q];
          f32x2 rlo = (f32x2){rv.x, rv.y}, rhi = (f32x2){rv.z, rv.w};
          PKFMA(acc, kreg2[2*q],   rlo);
          PKFMA(acc, kreg2[2*q+1], rhi);
        }
        part = acc.x + acc.y;
      }
      float s1 = __shfl_down(part, 1);
      float s2 = __shfl_down(part, 2);
      if (bval && SP == 0) z_lds[SROW] = -(part + s1 + s2);
    }
    __syncthreads();
    // stage C + update: A rows from LDS (conflict-free b128), z broadcast;
    // identity constraints on spare lanes
    {
      float part = 0.f;
      if (hasrow) {
        const float4* av = (const float4*)&nA[rowC * 84 + QC * 40];
        const float4* zb = (const float4*)&z_lds[QC * 40];
        f32x2 acc = {0.f, 0.f};
#pragma unroll
        for (int q = 0; q < 10; ++q) {
          float4 avv = av[q];
          float4 zv  = zb[q];
          f32x2 alo = (f32x2){avv.x, avv.y}, ahi = (f32x2){avv.z, avv.w};
          f32x2 zlo = (f32x2){zv.x, zv.y},  zhi = (f32x2){zv.z, zv.w};
          PKFMA(acc, alo, zlo);
          PKFMA(acc, ahi, zhi);
        }
        part = acc.x + acc.y;
      }
      float s1 = __shfl_down(part, 1);
      if (hasrow && QC == 0) {
        float gz = part + s1;
        if (rowC >= 81) gz -= z_lds[80 + (rowC - 81)];   // soft rows: -s term
        float v = gz + yor;
        float wv = fminf(v, h);
        u_lds[rowC] = RHO_C * (2.f * wv - v);
        yor = v - wv;
      }
      if (isx) {
        int zi = (eidx < 4) ? (80 + eidx) : (eidx - 4);
        float gz = -z_lds[zi];
        float v = gz + yor;
        float wv = fminf(v, h);
        u_lds[85 + eidx] = RHO_C * (2.f * wv - v);
        yor = v - wv;
      }
    }
    __syncthreads();
  }

  if (t < 80) outp[s * 80 + t] = z_lds[t];
}

extern "C" void kernel_launch(void* const* d_in, const int* in_sizes, int n_in,
                              void* d_out, int out_size, void* d_ws, size_t ws_size,
                              hipStream_t stream) {
  const float* xraw = (const float*)d_in[0];
  const float* Ag   = (const float*)d_in[1];
  const float* bg   = (const float*)d_in[2];
  const float* lowg = (const float*)d_in[3];
  float* outp = (float*)d_out;
  const int B = in_sizes[0] / 80;
  qp_admm_kernel<<<B, 256, 0, stream>>>(xraw, Ag, bg, lowg, outp);
}